// Round 8
// baseline (233.492 us; speedup 1.0000x reference)
//
#include <hip/hip_runtime.h>

// ---------------------------------------------------------------------------
// AttentionOnly fused block on MI355X (gfx950).
// Pipeline:
//   1. ln1_kernel:      resid_pre -> x_bf (bf16, LN'd)
//   2. transpose_w x4:  W_Q/W_K/W_V -> WqkvT [3072][1024] bf16 ; W_O -> WoT [1024][1024] bf16
//   3. gemm_qkv:        x_bf @ WqkvT^T -> Q,K,V bf16 [b][h][pos][64]
//                       (Q pre-scaled by log2e/8 -> scores live in log2 space)
//   4. vtrans_psum:     V -> Vt [b][h][64][2048] bf16  +  Psum[b][h][32][64] f32 per-tile col sums
//      vsuffix:         Psum -> Vsuf[b][h][33][64] f32 tile suffix sums
//   5. attn_kernel:     causal zero-fill-mask flash attention -> Z bf16 [4096][1024]
//                       R4 sync structure; qt chosen via bitrev5(j5) + 8*(bh&3)
//                       so co-resident blocks on a CU have BALANCED total work.
//   6. gemm_out64:      Z @ WoT^T + b_O + resid_pre -> resid_mid f32  (64x128 tile, 512 blocks)
//   7. ln2_kernel:      resid_mid + LN(resid_mid) -> d_out f32
// ---------------------------------------------------------------------------

typedef __attribute__((ext_vector_type(8))) short bf16x8_t;
typedef __attribute__((ext_vector_type(4))) float f32x4_t;
typedef unsigned short u16;
typedef unsigned int u32;

// async global->LDS, 16B per lane. LDS dest must be wave-uniform base + lane*16.
#define GLOAD16(src, dst) \
  __builtin_amdgcn_global_load_lds((const __attribute__((address_space(1))) void*)(src), \
                                   (__attribute__((address_space(3))) void*)(dst), 16, 0, 0)

__device__ __forceinline__ u16 f2bf(float f) {
    u32 x = __float_as_uint(f);
    return (u16)((x + 0x7fffu + ((x >> 16) & 1u)) >> 16);  // RNE
}
__device__ __forceinline__ float bf2f(u16 u) {
    return __uint_as_float(((u32)u) << 16);
}
// single-instruction f32->bf16 (RNE) via cvt_pk
__device__ __forceinline__ u16 f2bf_cvt(float f) {
    u32 r;
    asm("v_cvt_pk_bf16_f32 %0, %1, %1" : "=v"(r) : "v"(f));
    return (u16)r;
}

// ---------------------------------------------------------------------------
// 1. LayerNorm #1 -> bf16
// ---------------------------------------------------------------------------
__global__ __launch_bounds__(256) void ln1_kernel(const float* __restrict__ in,
                                                  const float* __restrict__ w,
                                                  const float* __restrict__ b,
                                                  u16* __restrict__ out) {
    const int r = blockIdx.x, tid = threadIdx.x, lane = tid & 63, wv = tid >> 6;
    const float4* row = (const float4*)(in + (size_t)r * 1024);
    float4 v = row[tid];
    float s1 = v.x + v.y + v.z + v.w;
    float s2 = v.x * v.x + v.y * v.y + v.z * v.z + v.w * v.w;
#pragma unroll
    for (int d = 1; d < 64; d <<= 1) { s1 += __shfl_xor(s1, d, 64); s2 += __shfl_xor(s2, d, 64); }
    __shared__ float r1[4], r2[4];
    if (lane == 0) { r1[wv] = s1; r2[wv] = s2; }
    __syncthreads();
    s1 = r1[0] + r1[1] + r1[2] + r1[3];
    s2 = r2[0] + r2[1] + r2[2] + r2[3];
    const float mean = s1 * (1.f / 1024.f);
    const float var  = s2 * (1.f / 1024.f) - mean * mean;
    const float inv  = rsqrtf(var + 1e-5f);
    float4 wv4 = ((const float4*)w)[tid], bv4 = ((const float4*)b)[tid];
    ushort4 o;
    o.x = f2bf((v.x - mean) * inv * wv4.x + bv4.x);
    o.y = f2bf((v.y - mean) * inv * wv4.y + bv4.y);
    o.z = f2bf((v.z - mean) * inv * wv4.z + bv4.z);
    o.w = f2bf((v.w - mean) * inv * wv4.w + bv4.w);
    ((ushort4*)(out + (size_t)r * 1024))[tid] = o;
}

// ---------------------------------------------------------------------------
// 2. Transposing fp32 -> bf16 weight conversion. In: [K_][N_] row-major (per z),
//    Out: [N_][K_] bf16 (per z). z strides: In K_*N_, Out N_*K_.
// ---------------------------------------------------------------------------
__global__ __launch_bounds__(256) void transpose_w(const float* __restrict__ In,
                                                   u16* __restrict__ Out,
                                                   int K_, int N_) {
    __shared__ float t[64][65];
    const int k0 = blockIdx.x * 64, n0 = blockIdx.y * 64, z = blockIdx.z, tid = threadIdx.x;
    In  += (size_t)z * K_ * N_;
    Out += (size_t)z * N_ * K_;
#pragma unroll
    for (int j = 0; j < 16; ++j) {
        int idx = tid + 256 * j; int rr = idx >> 6, cc = idx & 63;
        t[rr][cc] = In[(size_t)(k0 + rr) * N_ + n0 + cc];
    }
    __syncthreads();
#pragma unroll
    for (int j = 0; j < 16; ++j) {
        int idx = tid + 256 * j; int n = idx >> 6, k = idx & 63;
        Out[(size_t)(n0 + n) * K_ + k0 + k] = f2bf(t[k][n]);
    }
}

// ---------------------------------------------------------------------------
// Shared GEMM mainloop: C[128][128] += A[128 rows][K] * B^T (Bm is [N][K] n-major).
// LDS tiles are XOR-swizzled: logical (row, off) lives at row*128 + (off ^ ((row&7)<<4)).
// Staged with global_load_lds(16B): linear LDS dest, inverse-swizzled global source.
// ---------------------------------------------------------------------------
__device__ __forceinline__ void gemm_mainloop(const u16* __restrict__ A, const u16* __restrict__ Bm,
                                              int K, int rowA, int rowB,
                                              char* lA, char* lB, f32x4_t (&acc)[4][4]) {
    const int tid = threadIdx.x, lane = tid & 63, w = tid >> 6;
    const int wm = w >> 1, wn = w & 1, c = lane & 15, g = lane >> 4;
    const size_t strideB = (size_t)K * 2;
    const char* Ab = (const char*)A;
    const char* Bb = (const char*)Bm;
    const int nkt = K >> 6;  // BK = 64
    for (int kt = 0; kt < nkt; ++kt) {
#pragma unroll
        for (int it = 0; it < 4; ++it) {
            int T = it * 256 + tid;
            int row = T >> 3;
            int off = ((T & 7) << 4) ^ ((row & 7) << 4);  // inverse swizzle on source
            GLOAD16(Ab + (size_t)(rowA + row) * strideB + (kt << 7) + off, lA + T * 16);
            GLOAD16(Bb + (size_t)(rowB + row) * strideB + (kt << 7) + off, lB + T * 16);
        }
        __syncthreads();
#pragma unroll
        for (int kc = 0; kc < 2; ++kc) {
            bf16x8_t af[4], bfr[4];
#pragma unroll
            for (int ms = 0; ms < 4; ++ms) {
                int row = wm * 64 + ms * 16 + c;
                af[ms] = *(const bf16x8_t*)(lA + row * 128 + (((kc << 6) + (g << 4)) ^ ((row & 7) << 4)));
            }
#pragma unroll
            for (int ns = 0; ns < 4; ++ns) {
                int row = wn * 64 + ns * 16 + c;
                bfr[ns] = *(const bf16x8_t*)(lB + row * 128 + (((kc << 6) + (g << 4)) ^ ((row & 7) << 4)));
            }
            __builtin_amdgcn_s_setprio(1);
#pragma unroll
            for (int ms = 0; ms < 4; ++ms)
#pragma unroll
                for (int ns = 0; ns < 4; ++ns)
                    acc[ms][ns] = __builtin_amdgcn_mfma_f32_16x16x32_bf16(af[ms], bfr[ns], acc[ms][ns], 0, 0, 0);
            __builtin_amdgcn_s_setprio(0);
        }
        __syncthreads();
    }
}

// ---------------------------------------------------------------------------
// 3. QKV projection GEMM: M=4096, N=3072, K=1024; epilogue adds bias; Q scaled
//    by log2e/8 (scores end up in log2 space); stores bf16 to [b][h][pos][64].
// ---------------------------------------------------------------------------
__global__ __launch_bounds__(256) void gemm_qkv(const u16* __restrict__ A, const u16* __restrict__ Bm,
                                                const float* __restrict__ bQ, const float* __restrict__ bK,
                                                const float* __restrict__ bV,
                                                u16* __restrict__ Qo, u16* __restrict__ Ko,
                                                u16* __restrict__ Vo) {
    __shared__ char lA[16384], lB[16384];
    f32x4_t acc[4][4];
#pragma unroll
    for (int ms = 0; ms < 4; ++ms)
#pragma unroll
        for (int ns = 0; ns < 4; ++ns) acc[ms][ns] = (f32x4_t){0.f, 0.f, 0.f, 0.f};
    const int bm = blockIdx.x, bn = blockIdx.y;
    gemm_mainloop(A, Bm, 1024, bm * 128, bn * 128, lA, lB, acc);
    const int tid = threadIdx.x, lane = tid & 63, w = tid >> 6;
    const int wm = w >> 1, wn = w & 1, c = lane & 15, g = lane >> 4;
#pragma unroll
    for (int ms = 0; ms < 4; ++ms) {
#pragma unroll
        for (int ns = 0; ns < 4; ++ns) {
            int gcol = bn * 128 + wn * 64 + ns * 16 + c;
            int p = gcol >> 10;
            int rem = gcol & 1023;
            const float* bias = (p == 0) ? bQ : (p == 1) ? bK : bV;
            u16* dst = (p == 0) ? Qo : (p == 1) ? Ko : Vo;
            float bv = bias[rem];
            int h = rem >> 6, dh = rem & 63;
#pragma unroll
            for (int i = 0; i < 4; ++i) {
                int grow = bm * 128 + wm * 64 + ms * 16 + g * 4 + i;
                float val = acc[ms][ns][i] + bv;
                if (p == 0) val *= 0.18033688011112042f;  // (1/8)*log2(e): scores in log2 space
                int bb = grow >> 11, pos = grow & 2047;
                dst[((size_t)((bb << 4) + h) * 2048 + pos) * 64 + dh] = f2bf(val);
            }
        }
    }
}

// ---------------------------------------------------------------------------
// 4a. V transpose + per-tile column sums. One block per (tile, bh).
//     Vt[b][h][dh][pos];  Psum[b][h][t][dh] = sum_{p in tile t} V[p][dh]  (f32)
// ---------------------------------------------------------------------------
__global__ __launch_bounds__(256) void vtrans_psum(const u16* __restrict__ V,
                                                   u16* __restrict__ Vt,
                                                   float* __restrict__ Psum) {
    const int tile = blockIdx.x, bh = blockIdx.y, tid = threadIdx.x;
    const int q = tid >> 6, cc = tid & 63;
    const u16* src = V + ((size_t)bh * 2048 + tile * 64) * 64;
    u16* dst = Vt + (size_t)bh * 64 * 2048;
    __shared__ u16 tt[64][65];
    __shared__ float ps[4][64];
    float part = 0.f;
#pragma unroll
    for (int j = 0; j < 16; ++j) {
        int rr = q + 4 * j;                       // each thread: fixed column cc, 16 rows
        u16 val = src[(size_t)rr * 64 + cc];
        tt[rr][cc] = val;
        part += bf2f(val);
    }
    ps[q][cc] = part;
    __syncthreads();
#pragma unroll
    for (int j = 0; j < 16; ++j) {
        int idx = tid + 256 * j; int dh = idx >> 6, kk = idx & 63;
        dst[(size_t)dh * 2048 + tile * 64 + kk] = tt[kk][dh];
    }
    if (tid < 64)
        Psum[((size_t)bh * 32 + tile) * 64 + tid] = ps[0][tid] + ps[1][tid] + ps[2][tid] + ps[3][tid];
}

// ---------------------------------------------------------------------------
// 4b. Tile suffix scan: Vsuf[b][h][t][dh] = sum_{t' >= t} Psum[b][h][t'][dh];
//     Vsuf[32] = 0. One block per bh, 64 threads (one per dh).
// ---------------------------------------------------------------------------
__global__ __launch_bounds__(64) void vsuffix(const float* __restrict__ Psum,
                                              float* __restrict__ Vsuf) {
    const int bh = blockIdx.x, dh = threadIdx.x;
    const float* ps = Psum + (size_t)bh * 32 * 64;
    float* suf = Vsuf + (size_t)bh * 33 * 64;
    float run = 0.f;
    suf[32 * 64 + dh] = 0.f;
    for (int t = 31; t >= 0; --t) {
        run += ps[t * 64 + dh];
        suf[t * 64 + dh] = run;
    }
}

// ---------------------------------------------------------------------------
// 5. Flash attention, ZERO-FILL causal mask, exp2-space softmax.
//    R4 known-good sync structure: one q-tile per block, grid 1024.
//    qt map: bitrev5(j5) + 8*(bh&3) (mod 32) — bijective per bh, and the
//    blocks co-resident on one CU (same j5, 4 consecutive bh under stride-32
//    round-robin; or 4 consecutive j5) get qt values spread by ~8/16/24 so
//    per-CU total work is ~52-80 iters instead of 4-128 (tail balance).
//    - scores pre-scaled by log2e -> p = exp2(s - m); m_ init 0 (m_>=0 invariant)
//    - l_ lane-partial (16 keys/lane); reduced once in the epilogue
//    Masked in-tile scores are set to 0.0 and INCLUDED (weight e^{-m}); keys
//    beyond the processed tiles are folded in closed form via Vsuf.
// ---------------------------------------------------------------------------
__global__ __launch_bounds__(256) void attn_kernel(const u16* __restrict__ Q, const u16* __restrict__ Kb,
                                                   const u16* __restrict__ Vt, const float* __restrict__ Vsuf,
                                                   u16* __restrict__ Z) {
    __shared__ char lK[2][8192], lV[2][8192], lP[4][2048];
    const int tid = threadIdx.x, lane = tid & 63, w = tid >> 6, c = lane & 15, g = lane >> 4;
    // XCD-chunked bijective swizzle: 1024 blocks, 8 XCDs -> 128 consecutive
    // logical blocks per XCD so same-bh blocks share one L2.
    const int logical = (blockIdx.x & 7) * 128 + (blockIdx.x >> 3);
    const int bh = logical >> 5;
    const int j5 = logical & 31;
    const int r5 = ((j5 & 1) << 4) | ((j5 & 2) << 2) | (j5 & 4) | ((j5 & 8) >> 2) | ((j5 & 16) >> 4);
    const int qt = (r5 + ((logical >> 5) & 3) * 8) & 31;  // balanced work per CU
    const char* Kp = (const char*)(Kb + (size_t)bh * 2048 * 64);
    const char* Vp = (const char*)(Vt + (size_t)bh * 64 * 2048);
    const u16* Qp = Q + (size_t)bh * 2048 * 64;

    const int qrow = qt * 64 + w * 16 + c;
    bf16x8_t qf0 = *(const bf16x8_t*)(Qp + (size_t)qrow * 64 + g * 8);
    bf16x8_t qf1 = *(const bf16x8_t*)(Qp + (size_t)qrow * 64 + 32 + g * 8);

    float m_[4], l_[4];
    f32x4_t zacc[4];
#pragma unroll
    for (int i = 0; i < 4; ++i) { m_[i] = 0.f; l_[i] = 0.f; }  // m_=0 valid guess; m_>=0 invariant
#pragma unroll
    for (int jd = 0; jd < 4; ++jd) zacc[jd] = (f32x4_t){0.f, 0.f, 0.f, 0.f};

    const int nkv = qt + 1;
    auto STAGE = [&](int kv, int buf) {
#pragma unroll
        for (int it = 0; it < 2; ++it) {
            int T = it * 256 + tid;
            int row = T >> 3;
            int off = ((T & 7) << 4) ^ ((row & 7) << 4);
            GLOAD16(Kp + (size_t)(kv * 64 + row) * 128 + off, &lK[buf][0] + T * 16);
            GLOAD16(Vp + (size_t)row * 4096 + kv * 128 + off, &lV[buf][0] + T * 16);
        }
    };

    STAGE(0, 0);
    __syncthreads();  // implicit vmcnt(0) drain completes tile 0

    for (int kv = 0; kv < nkv; ++kv) {
        const int cur = kv & 1;
        if (kv + 1 < nkv) STAGE(kv + 1, cur ^ 1);  // prefetch overlaps compute below
        const char* K0 = &lK[cur][0];
        const char* V0 = &lV[cur][0];

        // scores: 16 q x 64 keys per wave (log2 space)
        f32x4_t s[4];
        __builtin_amdgcn_s_setprio(1);
#pragma unroll
        for (int j = 0; j < 4; ++j) {
            int kr = j * 16 + c;
            bf16x8_t k0 = *(const bf16x8_t*)(K0 + kr * 128 + (((g << 4)) ^ ((kr & 7) << 4)));
            bf16x8_t k1 = *(const bf16x8_t*)(K0 + kr * 128 + ((64 + (g << 4)) ^ ((kr & 7) << 4)));
            f32x4_t zz = (f32x4_t){0.f, 0.f, 0.f, 0.f};
            s[j] = __builtin_amdgcn_mfma_f32_16x16x32_bf16(qf0, k0, zz, 0, 0, 0);
            s[j] = __builtin_amdgcn_mfma_f32_16x16x32_bf16(qf1, k1, s[j], 0, 0, 0);
        }
        __builtin_amdgcn_s_setprio(0);
        if (kv == qt) {  // diagonal: zero-fill (NOT -inf) masked entries, keep in softmax
#pragma unroll
            for (int j = 0; j < 4; ++j)
#pragma unroll
                for (int i = 0; i < 4; ++i) {
                    int key = kv * 64 + j * 16 + c;
                    int qr = qt * 64 + w * 16 + g * 4 + i;
                    if (key > qr) s[j][i] = 0.f;
                }
        }
        // --- online softmax, defer-max (THR=11 in log2 space ~ e^7.6) ---
        float pm[4];
#pragma unroll
        for (int i = 0; i < 4; ++i)
            pm[i] = fmaxf(fmaxf(s[0][i], s[1][i]), fmaxf(s[2][i], s[3][i]));
        int ok = 1;
#pragma unroll
        for (int i = 0; i < 4; ++i) ok &= (pm[i] <= m_[i] + 11.f);
        if (__builtin_expect(__all(ok), 1)) {
            // fast path: keep old max, no reduce, no rescale; l_ lane-partial
#pragma unroll
            for (int j = 0; j < 4; ++j)
#pragma unroll
                for (int i = 0; i < 4; ++i) {
                    float p = exp2f(s[j][i] - m_[i]);
                    s[j][i] = p;
                    l_[i] += p;
                }
        } else {
            // slow path (rare): full max-reduce + rescale of lane-partial state
            float mn[4], sc[4];
#pragma unroll
            for (int d = 1; d < 16; d <<= 1)
#pragma unroll
                for (int i = 0; i < 4; ++i) pm[i] = fmaxf(pm[i], __shfl_xor(pm[i], d, 64));
#pragma unroll
            for (int i = 0; i < 4; ++i) {
                mn[i] = fmaxf(m_[i], pm[i]);
                sc[i] = exp2f(m_[i] - mn[i]);
            }
#pragma unroll
            for (int j = 0; j < 4; ++j)
#pragma unroll
                for (int i = 0; i < 4; ++i) {
                    float p = exp2f(s[j][i] - mn[i]);
                    s[j][i] = p;
                }
#pragma unroll
            for (int i = 0; i < 4; ++i) {
                l_[i] = l_[i] * sc[i] + (s[0][i] + s[1][i] + s[2][i] + s[3][i]);
                m_[i] = mn[i];
            }
#pragma unroll
            for (int jd = 0; jd < 4; ++jd)
#pragma unroll
                for (int i = 0; i < 4; ++i) zacc[jd][i] *= sc[i];
        }

        // P -> wave-private swizzled LDS (bf16), then consume as MFMA A-frags
        char* Pw = lP[w];
#pragma unroll
        for (int j = 0; j < 4; ++j)
#pragma unroll
            for (int i = 0; i < 4; ++i) {
                int rq = g * 4 + i;
                *(u16*)(Pw + rq * 128 + (((j << 5) + (c << 1)) ^ ((rq & 7) << 4))) = f2bf_cvt(s[j][i]);
            }
        bf16x8_t pf[2];
#pragma unroll
        for (int kc = 0; kc < 2; ++kc)
            pf[kc] = *(const bf16x8_t*)(Pw + c * 128 + (((kc << 6) + (g << 4)) ^ ((c & 7) << 4)));
        __builtin_amdgcn_s_setprio(1);
#pragma unroll
        for (int jd = 0; jd < 4; ++jd) {
            int vr = jd * 16 + c;
#pragma unroll
            for (int kc = 0; kc < 2; ++kc) {
                bf16x8_t vf = *(const bf16x8_t*)(V0 + vr * 128 + (((kc << 6) + (g << 4)) ^ ((vr & 7) << 4)));
                zacc[jd] = __builtin_amdgcn_mfma_f32_16x16x32_bf16(pf[kc], vf, zacc[jd], 0, 0, 0);
            }
        }
        __builtin_amdgcn_s_setprio(0);
        __syncthreads();  // drains prefetch (vmcnt) + guards buffer reuse
    }

    // epilogue: reduce lane-partial l_ across the 16-lane row group (once)
#pragma unroll
    for (int d = 1; d < 16; d <<= 1)
#pragma unroll
        for (int i = 0; i < 4; ++i) l_[i] += __shfl_xor(l_[i], d, 64);

    // fold the fully-masked suffix: Cout keys each with score 0.0.
    // m_ >= 0 invariant -> scf = 1.
    const int Cout = 2048 - nkv * 64;
    const float* suf = Vsuf + (size_t)bh * 33 * 64 + nkv * 64;
    float s0f[4], lf[4];
#pragma unroll
    for (int i = 0; i < 4; ++i) {
        s0f[i] = exp2f(-m_[i]);
        lf[i] = l_[i] + (float)Cout * s0f[i];
    }
    const int bb = bh >> 4, hh = bh & 15;
#pragma unroll
    for (int jd = 0; jd < 4; ++jd) {
        float sv = suf[jd * 16 + c];
#pragma unroll
        for (int i = 0; i < 4; ++i) {
            float z = (zacc[jd][i] + s0f[i] * sv) / lf[i];
            size_t rowz = (size_t)bb * 2048 + qt * 64 + w * 16 + g * 4 + i;
            Z[rowz * 1024 + hh * 64 + jd * 16 + c] = f2bf_cvt(z);
        }
    }
}

// ---------------------------------------------------------------------------
// 6. Output projection GEMM, 64x128 tile: M=4096, N=1024, K=1024.
//    512 blocks (2/CU). Per wave: 32x64 (2x4 frags of 16x16).
//    Epilogue: + b_O + resid_pre -> f32.
// ---------------------------------------------------------------------------
__global__ __launch_bounds__(256) void gemm_out64(const u16* __restrict__ A, const u16* __restrict__ Bm,
                                                  const float* __restrict__ bO,
                                                  const float* __restrict__ resid,
                                                  float* __restrict__ outMid) {
    __shared__ char lA[8192], lB[16384];
    f32x4_t acc[2][4];
#pragma unroll
    for (int ms = 0; ms < 2; ++ms)
#pragma unroll
        for (int ns = 0; ns < 4; ++ns) acc[ms][ns] = (f32x4_t){0.f, 0.f, 0.f, 0.f};
    const int bm = blockIdx.x, bn = blockIdx.y;
    const int tid = threadIdx.x, lane = tid & 63, w = tid >> 6;
    const int wm = w >> 1, wn = w & 1, c = lane & 15, g = lane >> 4;
    const char* Ab = (const char*)A;   // [4096][1024] bf16, row stride 2048 B
    const char* Bb = (const char*)Bm;  // WoT [1024][1024] bf16, row stride 2048 B
    const int rowA0 = bm * 64, rowB0 = bn * 128;
    for (int kt = 0; kt < 16; ++kt) {
#pragma unroll
        for (int it = 0; it < 2; ++it) {       // A: 64 rows x 128 B
            int T = it * 256 + tid;
            int row = T >> 3;
            int off = ((T & 7) << 4) ^ ((row & 7) << 4);
            GLOAD16(Ab + (size_t)(rowA0 + row) * 2048 + (kt << 7) + off, lA + T * 16);
        }
#pragma unroll
        for (int it = 0; it < 4; ++it) {       // B: 128 rows x 128 B
            int T = it * 256 + tid;
            int row = T >> 3;
            int off = ((T & 7) << 4) ^ ((row & 7) << 4);
            GLOAD16(Bb + (size_t)(rowB0 + row) * 2048 + (kt << 7) + off, lB + T * 16);
        }
        __syncthreads();
#pragma unroll
        for (int kc = 0; kc < 2; ++kc) {
            bf16x8_t af[2], bfr[4];
#pragma unroll
            for (int ms = 0; ms < 2; ++ms) {
                int row = wm * 32 + ms * 16 + c;
                af[ms] = *(const bf16x8_t*)(lA + row * 128 + (((kc << 6) + (g << 4)) ^ ((row & 7) << 4)));
            }
#pragma unroll
            for (int ns = 0; ns < 4; ++ns) {
                int row = wn * 64 + ns * 16 + c;
                bfr[ns] = *(const bf16x8_t*)(lB + row * 128 + (((kc << 6) + (g << 4)) ^ ((row & 7) << 4)));
            }
            __builtin_amdgcn_s_setprio(1);
#pragma unroll
            for (int ms = 0; ms < 2; ++ms)
#pragma unroll
                for (int ns = 0; ns < 4; ++ns)
                    acc[ms][ns] = __builtin_amdgcn_mfma_f32_16x16x32_bf16(af[ms], bfr[ns], acc[ms][ns], 0, 0, 0);
            __builtin_amdgcn_s_setprio(0);
        }
        __syncthreads();
    }
#pragma unroll
    for (int ms = 0; ms < 2; ++ms) {
#pragma unroll
        for (int ns = 0; ns < 4; ++ns) {
            int gcol = bn * 128 + wn * 64 + ns * 16 + c;
            float bo = bO[gcol];
#pragma unroll
            for (int i = 0; i < 4; ++i) {
                int grow = bm * 64 + wm * 32 + ms * 16 + g * 4 + i;
                size_t o = (size_t)grow * 1024 + gcol;
                outMid[o] = acc[ms][ns][i] + bo + resid[o];
            }
        }
    }
}

// ---------------------------------------------------------------------------
// 7. LayerNorm #2 + residual: out = mid + LN(mid)*w + b
// ---------------------------------------------------------------------------
__global__ __launch_bounds__(256) void ln2_kernel(const float* __restrict__ mid,
                                                  const float* __restrict__ w,
                                                  const float* __restrict__ b,
                                                  float* __restrict__ out) {
    const int r = blockIdx.x, tid = threadIdx.x, lane = tid & 63, wv = tid >> 6;
    const float4* row = (const float4*)(mid + (size_t)r * 1024);
    float4 v = row[tid];
    float s1 = v.x + v.y + v.z + v.w;
    float s2 = v.x * v.x + v.y * v.y + v.z * v.z + v.w * v.w;
#pragma unroll
    for (int d = 1; d < 64; d <<= 1) { s1 += __shfl_xor(s1, d, 64); s2 += __shfl_xor(s2, d, 64); }
    __shared__ float r1[4], r2[4];
    if (lane == 0) { r1[wv] = s1; r2[wv] = s2; }
    __syncthreads();
    s1 = r1[0] + r1[1] + r1[2] + r1[3];
    s2 = r2[0] + r2[1] + r2[2] + r2[3];
    const float mean = s1 * (1.f / 1024.f);
    const float var  = s2 * (1.f / 1024.f) - mean * mean;
    const float inv  = rsqrtf(var + 1e-5f);
    float4 wv4 = ((const float4*)w)[tid], bv4 = ((const float4*)b)[tid];
    float4 o;
    o.x = v.x + (v.x - mean) * inv * wv4.x + bv4.x;
    o.y = v.y + (v.y - mean) * inv * wv4.y + bv4.y;
    o.z = v.z + (v.z - mean) * inv * wv4.z + bv4.z;
    o.w = v.w + (v.w - mean) * inv * wv4.w + bv4.w;
    ((float4*)(out + (size_t)r * 1024))[tid] = o;
}

// ---------------------------------------------------------------------------
// Launch
// ---------------------------------------------------------------------------
extern "C" void kernel_launch(void* const* d_in, const int* in_sizes, int n_in,
                              void* d_out, int out_size, void* d_ws, size_t ws_size,
                              hipStream_t stream) {
    const float* resid_pre = (const float*)d_in[0];
    const float* W_Q  = (const float*)d_in[1];
    const float* b_Q  = (const float*)d_in[2];
    const float* W_K  = (const float*)d_in[3];
    const float* b_K  = (const float*)d_in[4];
    const float* W_V  = (const float*)d_in[5];
    const float* b_V  = (const float*)d_in[6];
    const float* W_O  = (const float*)d_in[7];
    const float* b_O  = (const float*)d_in[8];
    const float* ln1_w = (const float*)d_in[9];
    const float* ln1_b = (const float*)d_in[10];
    const float* ln2_w = (const float*)d_in[11];
    const float* ln2_b = (const float*)d_in[12];

    char* ws = (char*)d_ws;
    const size_t MB = 1u << 20;
    u16*  x_bf   = (u16*)(ws + 0);            // 8 MB   (dead after gemm_qkv)
    u16*  WqkvT  = (u16*)(ws + 8 * MB);       // 6 MB   (dead after gemm_qkv)
    u16*  Qb     = (u16*)(ws + 16 * MB);      // 8 MB
    u16*  Kb     = (u16*)(ws + 24 * MB);      // 8 MB
    u16*  Vb     = (u16*)(ws + 32 * MB);      // 8 MB
    u16*  Vt     = (u16*)(ws + 40 * MB);      // 8 MB
    float* Vsuf  = (float*)(ws + 48 * MB);            // 270 KB
    float* Psum  = (float*)(ws + 48 * MB + 512 * 1024); // 256 KB
    u16*  Zb     = (u16*)(ws + 49 * MB);      // 8 MB
    u16*  WoT    = (u16*)(ws + 57 * MB);      // 2 MB
    float* resid_mid = (float*)(ws + 0);      // 16 MB, overlaps dead x_bf/WqkvT

    ln1_kernel<<<dim3(4096), dim3(256), 0, stream>>>(resid_pre, ln1_w, ln1_b, x_bf);

    transpose_w<<<dim3(16, 1, 16), dim3(256), 0, stream>>>(W_Q, WqkvT,                1024, 64);
    transpose_w<<<dim3(16, 1, 16), dim3(256), 0, stream>>>(W_K, WqkvT + 1024 * 1024,  1024, 64);
    transpose_w<<<dim3(16, 1, 16), dim3(256), 0, stream>>>(W_V, WqkvT + 2048 * 1024,  1024, 64);
    transpose_w<<<dim3(16, 16, 1), dim3(256), 0, stream>>>(W_O, WoT, 1024, 1024);

    gemm_qkv<<<dim3(32, 24), dim3(256), 0, stream>>>(x_bf, WqkvT, b_Q, b_K, b_V, Qb, Kb, Vb);

    vtrans_psum<<<dim3(32, 32), dim3(256), 0, stream>>>(Vb, Vt, Psum);
    vsuffix<<<dim3(32), dim3(64), 0, stream>>>(Psum, Vsuf);

    attn_kernel<<<dim3(1024), dim3(256), 0, stream>>>(Qb, Kb, Vt, Vsuf, Zb);

    gemm_out64<<<dim3(64, 8), dim3(256), 0, stream>>>(Zb, WoT, b_O, resid_pre, resid_mid);

    ln2_kernel<<<dim3(4096), dim3(256), 0, stream>>>(resid_mid, ln2_w, ln2_b, (float*)d_out);
}

// Round 9
// 231.912 us; speedup vs baseline: 1.0068x; 1.0068x over previous
//
#include <hip/hip_runtime.h>

// ---------------------------------------------------------------------------
// AttentionOnly fused block on MI355X (gfx950).
// Pipeline:
//   1. ln1_kernel:      resid_pre -> x_bf (bf16, LN'd)
//   2. transpose_w x4:  W_Q/W_K/W_V -> WqkvT [3072][1024] bf16 ; W_O -> WoT [1024][1024] bf16
//   3. gemm_qkv:        x_bf @ WqkvT^T -> Q,K,V bf16 [b][h][pos][64]
//                       (Q pre-scaled by log2e/8 -> scores live in log2 space)
//   4. vtrans_psum:     V -> Vt [b][h][64][2048] bf16  +  Psum[b][h][32][64] f32 per-tile col sums
//      vsuffix:         Psum -> Vsuf[b][h][33][64] f32 tile suffix sums
//   5. attn_kernel:     causal zero-fill-mask flash attention (R4 inner loop).
//                       qt>=16 tiles SPLIT into two blocks over disjoint KV halves
//                       writing (m,l,zacc) partials; qt<16 write Z directly.
//                       Grid 1536 (6/CU -> dispatcher refill), max block 16 iters.
//      attn_combine:    flash-merge partials + suffix fold + divide -> Z rows 1024+.
//   6. gemm_out64:      Z @ WoT^T + b_O + resid_pre -> resid_mid f32  (64x128 tile, 512 blocks)
//   7. ln2_kernel:      resid_mid + LN(resid_mid) -> d_out f32
// ---------------------------------------------------------------------------

typedef __attribute__((ext_vector_type(8))) short bf16x8_t;
typedef __attribute__((ext_vector_type(4))) float f32x4_t;
typedef unsigned short u16;
typedef unsigned int u32;

// async global->LDS, 16B per lane. LDS dest must be wave-uniform base + lane*16.
#define GLOAD16(src, dst) \
  __builtin_amdgcn_global_load_lds((const __attribute__((address_space(1))) void*)(src), \
                                   (__attribute__((address_space(3))) void*)(dst), 16, 0, 0)

__device__ __forceinline__ u16 f2bf(float f) {
    u32 x = __float_as_uint(f);
    return (u16)((x + 0x7fffu + ((x >> 16) & 1u)) >> 16);  // RNE
}
__device__ __forceinline__ float bf2f(u16 u) {
    return __uint_as_float(((u32)u) << 16);
}
// single-instruction f32->bf16 (RNE) via cvt_pk
__device__ __forceinline__ u16 f2bf_cvt(float f) {
    u32 r;
    asm("v_cvt_pk_bf16_f32 %0, %1, %1" : "=v"(r) : "v"(f));
    return (u16)r;
}

// ---------------------------------------------------------------------------
// 1. LayerNorm #1 -> bf16
// ---------------------------------------------------------------------------
__global__ __launch_bounds__(256) void ln1_kernel(const float* __restrict__ in,
                                                  const float* __restrict__ w,
                                                  const float* __restrict__ b,
                                                  u16* __restrict__ out) {
    const int r = blockIdx.x, tid = threadIdx.x, lane = tid & 63, wv = tid >> 6;
    const float4* row = (const float4*)(in + (size_t)r * 1024);
    float4 v = row[tid];
    float s1 = v.x + v.y + v.z + v.w;
    float s2 = v.x * v.x + v.y * v.y + v.z * v.z + v.w * v.w;
#pragma unroll
    for (int d = 1; d < 64; d <<= 1) { s1 += __shfl_xor(s1, d, 64); s2 += __shfl_xor(s2, d, 64); }
    __shared__ float r1[4], r2[4];
    if (lane == 0) { r1[wv] = s1; r2[wv] = s2; }
    __syncthreads();
    s1 = r1[0] + r1[1] + r1[2] + r1[3];
    s2 = r2[0] + r2[1] + r2[2] + r2[3];
    const float mean = s1 * (1.f / 1024.f);
    const float var  = s2 * (1.f / 1024.f) - mean * mean;
    const float inv  = rsqrtf(var + 1e-5f);
    float4 wv4 = ((const float4*)w)[tid], bv4 = ((const float4*)b)[tid];
    ushort4 o;
    o.x = f2bf((v.x - mean) * inv * wv4.x + bv4.x);
    o.y = f2bf((v.y - mean) * inv * wv4.y + bv4.y);
    o.z = f2bf((v.z - mean) * inv * wv4.z + bv4.z);
    o.w = f2bf((v.w - mean) * inv * wv4.w + bv4.w);
    ((ushort4*)(out + (size_t)r * 1024))[tid] = o;
}

// ---------------------------------------------------------------------------
// 2. Transposing fp32 -> bf16 weight conversion. In: [K_][N_] row-major (per z),
//    Out: [N_][K_] bf16 (per z). z strides: In K_*N_, Out N_*K_.
// ---------------------------------------------------------------------------
__global__ __launch_bounds__(256) void transpose_w(const float* __restrict__ In,
                                                   u16* __restrict__ Out,
                                                   int K_, int N_) {
    __shared__ float t[64][65];
    const int k0 = blockIdx.x * 64, n0 = blockIdx.y * 64, z = blockIdx.z, tid = threadIdx.x;
    In  += (size_t)z * K_ * N_;
    Out += (size_t)z * N_ * K_;
#pragma unroll
    for (int j = 0; j < 16; ++j) {
        int idx = tid + 256 * j; int rr = idx >> 6, cc = idx & 63;
        t[rr][cc] = In[(size_t)(k0 + rr) * N_ + n0 + cc];
    }
    __syncthreads();
#pragma unroll
    for (int j = 0; j < 16; ++j) {
        int idx = tid + 256 * j; int n = idx >> 6, k = idx & 63;
        Out[(size_t)(n0 + n) * K_ + k0 + k] = f2bf(t[k][n]);
    }
}

// ---------------------------------------------------------------------------
// Shared GEMM mainloop: C[128][128] += A[128 rows][K] * B^T (Bm is [N][K] n-major).
// LDS tiles are XOR-swizzled: logical (row, off) lives at row*128 + (off ^ ((row&7)<<4)).
// Staged with global_load_lds(16B): linear LDS dest, inverse-swizzled global source.
// ---------------------------------------------------------------------------
__device__ __forceinline__ void gemm_mainloop(const u16* __restrict__ A, const u16* __restrict__ Bm,
                                              int K, int rowA, int rowB,
                                              char* lA, char* lB, f32x4_t (&acc)[4][4]) {
    const int tid = threadIdx.x, lane = tid & 63, w = tid >> 6;
    const int wm = w >> 1, wn = w & 1, c = lane & 15, g = lane >> 4;
    const size_t strideB = (size_t)K * 2;
    const char* Ab = (const char*)A;
    const char* Bb = (const char*)Bm;
    const int nkt = K >> 6;  // BK = 64
    for (int kt = 0; kt < nkt; ++kt) {
#pragma unroll
        for (int it = 0; it < 4; ++it) {
            int T = it * 256 + tid;
            int row = T >> 3;
            int off = ((T & 7) << 4) ^ ((row & 7) << 4);  // inverse swizzle on source
            GLOAD16(Ab + (size_t)(rowA + row) * strideB + (kt << 7) + off, lA + T * 16);
            GLOAD16(Bb + (size_t)(rowB + row) * strideB + (kt << 7) + off, lB + T * 16);
        }
        __syncthreads();
#pragma unroll
        for (int kc = 0; kc < 2; ++kc) {
            bf16x8_t af[4], bfr[4];
#pragma unroll
            for (int ms = 0; ms < 4; ++ms) {
                int row = wm * 64 + ms * 16 + c;
                af[ms] = *(const bf16x8_t*)(lA + row * 128 + (((kc << 6) + (g << 4)) ^ ((row & 7) << 4)));
            }
#pragma unroll
            for (int ns = 0; ns < 4; ++ns) {
                int row = wn * 64 + ns * 16 + c;
                bfr[ns] = *(const bf16x8_t*)(lB + row * 128 + (((kc << 6) + (g << 4)) ^ ((row & 7) << 4)));
            }
            __builtin_amdgcn_s_setprio(1);
#pragma unroll
            for (int ms = 0; ms < 4; ++ms)
#pragma unroll
                for (int ns = 0; ns < 4; ++ns)
                    acc[ms][ns] = __builtin_amdgcn_mfma_f32_16x16x32_bf16(af[ms], bfr[ns], acc[ms][ns], 0, 0, 0);
            __builtin_amdgcn_s_setprio(0);
        }
        __syncthreads();
    }
}

// ---------------------------------------------------------------------------
// 3. QKV projection GEMM: M=4096, N=3072, K=1024; epilogue adds bias; Q scaled
//    by log2e/8 (scores end up in log2 space); stores bf16 to [b][h][pos][64].
// ---------------------------------------------------------------------------
__global__ __launch_bounds__(256) void gemm_qkv(const u16* __restrict__ A, const u16* __restrict__ Bm,
                                                const float* __restrict__ bQ, const float* __restrict__ bK,
                                                const float* __restrict__ bV,
                                                u16* __restrict__ Qo, u16* __restrict__ Ko,
                                                u16* __restrict__ Vo) {
    __shared__ char lA[16384], lB[16384];
    f32x4_t acc[4][4];
#pragma unroll
    for (int ms = 0; ms < 4; ++ms)
#pragma unroll
        for (int ns = 0; ns < 4; ++ns) acc[ms][ns] = (f32x4_t){0.f, 0.f, 0.f, 0.f};
    const int bm = blockIdx.x, bn = blockIdx.y;
    gemm_mainloop(A, Bm, 1024, bm * 128, bn * 128, lA, lB, acc);
    const int tid = threadIdx.x, lane = tid & 63, w = tid >> 6;
    const int wm = w >> 1, wn = w & 1, c = lane & 15, g = lane >> 4;
#pragma unroll
    for (int ms = 0; ms < 4; ++ms) {
#pragma unroll
        for (int ns = 0; ns < 4; ++ns) {
            int gcol = bn * 128 + wn * 64 + ns * 16 + c;
            int p = gcol >> 10;
            int rem = gcol & 1023;
            const float* bias = (p == 0) ? bQ : (p == 1) ? bK : bV;
            u16* dst = (p == 0) ? Qo : (p == 1) ? Ko : Vo;
            float bv = bias[rem];
            int h = rem >> 6, dh = rem & 63;
#pragma unroll
            for (int i = 0; i < 4; ++i) {
                int grow = bm * 128 + wm * 64 + ms * 16 + g * 4 + i;
                float val = acc[ms][ns][i] + bv;
                if (p == 0) val *= 0.18033688011112042f;  // (1/8)*log2(e): scores in log2 space
                int bb = grow >> 11, pos = grow & 2047;
                dst[((size_t)((bb << 4) + h) * 2048 + pos) * 64 + dh] = f2bf(val);
            }
        }
    }
}

// ---------------------------------------------------------------------------
// 4a. V transpose + per-tile column sums. One block per (tile, bh).
// ---------------------------------------------------------------------------
__global__ __launch_bounds__(256) void vtrans_psum(const u16* __restrict__ V,
                                                   u16* __restrict__ Vt,
                                                   float* __restrict__ Psum) {
    const int tile = blockIdx.x, bh = blockIdx.y, tid = threadIdx.x;
    const int q = tid >> 6, cc = tid & 63;
    const u16* src = V + ((size_t)bh * 2048 + tile * 64) * 64;
    u16* dst = Vt + (size_t)bh * 64 * 2048;
    __shared__ u16 tt[64][65];
    __shared__ float ps[4][64];
    float part = 0.f;
#pragma unroll
    for (int j = 0; j < 16; ++j) {
        int rr = q + 4 * j;                       // each thread: fixed column cc, 16 rows
        u16 val = src[(size_t)rr * 64 + cc];
        tt[rr][cc] = val;
        part += bf2f(val);
    }
    ps[q][cc] = part;
    __syncthreads();
#pragma unroll
    for (int j = 0; j < 16; ++j) {
        int idx = tid + 256 * j; int dh = idx >> 6, kk = idx & 63;
        dst[(size_t)dh * 2048 + tile * 64 + kk] = tt[kk][dh];
    }
    if (tid < 64)
        Psum[((size_t)bh * 32 + tile) * 64 + tid] = ps[0][tid] + ps[1][tid] + ps[2][tid] + ps[3][tid];
}

// ---------------------------------------------------------------------------
// 4b. Tile suffix scan: Vsuf[b][h][t][dh] = sum_{t' >= t} Psum[b][h][t'][dh].
// ---------------------------------------------------------------------------
__global__ __launch_bounds__(64) void vsuffix(const float* __restrict__ Psum,
                                              float* __restrict__ Vsuf) {
    const int bh = blockIdx.x, dh = threadIdx.x;
    const float* ps = Psum + (size_t)bh * 32 * 64;
    float* suf = Vsuf + (size_t)bh * 33 * 64;
    float run = 0.f;
    suf[32 * 64 + dh] = 0.f;
    for (int t = 31; t >= 0; --t) {
        run += ps[t * 64 + dh];
        suf[t * 64 + dh] = run;
    }
}

// ---------------------------------------------------------------------------
// 5. Flash attention, ZERO-FILL causal mask, exp2-space softmax.
//    R4 inner loop (unchanged sync structure). Grid 1536:
//      per XCD chunk of 192: 4 bh x 48 sub-blocks s:
//        s <  32: SPLIT block for qt = 31 - (s>>1), half = s&1 (heavy first)
//        s >= 32: FULL block for qt = 47 - s  (15..0)
//    Split halves cover disjoint KV ranges [0,h1) / [h1,nkv), h1 = ceil(nkv/2);
//    they write unnormalized partials (Mp, Lp, Zp); attn_combine merges.
//    - scores pre-scaled by log2e -> p = exp2(s - m); m_ init 0 (m_>=0 invariant)
//    - l_ lane-partial (16 keys/lane); reduced once in the epilogue
//    Masked in-tile scores are set to 0.0 and INCLUDED (weight e^{-m}); keys
//    beyond the processed tiles are folded via Vsuf (in combine for split rows).
// ---------------------------------------------------------------------------
__global__ __launch_bounds__(256) void attn_kernel(const u16* __restrict__ Q, const u16* __restrict__ Kb,
                                                   const u16* __restrict__ Vt, const float* __restrict__ Vsuf,
                                                   u16* __restrict__ Z, u16* __restrict__ Zp,
                                                   float* __restrict__ Mp, float* __restrict__ Lp) {
    __shared__ char lK[2][8192], lV[2][8192], lP[4][2048];
    const int tid = threadIdx.x, lane = tid & 63, w = tid >> 6, c = lane & 15, g = lane >> 4;
    const int logical = (blockIdx.x & 7) * 192 + (blockIdx.x >> 3);  // 8 XCD chunks of 192
    const int bh = logical / 48;
    const int s48 = logical % 48;
    int qt, half;
    if (s48 < 32) { qt = 31 - (s48 >> 1); half = s48 & 1; }  // split, heavy first
    else          { qt = 47 - s48;        half = -1;      }  // full, qt 15..0
    const int nkv = qt + 1;
    const int h1 = (nkv + 1) >> 1;
    const int kv0 = (half == 1) ? h1 : 0;
    const int kv1 = (half == 0) ? h1 : nkv;

    const char* Kp = (const char*)(Kb + (size_t)bh * 2048 * 64);
    const char* Vp = (const char*)(Vt + (size_t)bh * 64 * 2048);
    const u16* Qp = Q + (size_t)bh * 2048 * 64;

    const int qrow = qt * 64 + w * 16 + c;
    bf16x8_t qf0 = *(const bf16x8_t*)(Qp + (size_t)qrow * 64 + g * 8);
    bf16x8_t qf1 = *(const bf16x8_t*)(Qp + (size_t)qrow * 64 + 32 + g * 8);

    float m_[4], l_[4];
    f32x4_t zacc[4];
#pragma unroll
    for (int i = 0; i < 4; ++i) { m_[i] = 0.f; l_[i] = 0.f; }  // m_=0 valid guess; m_>=0 invariant
#pragma unroll
    for (int jd = 0; jd < 4; ++jd) zacc[jd] = (f32x4_t){0.f, 0.f, 0.f, 0.f};

    auto STAGE = [&](int kv, int buf) {
#pragma unroll
        for (int it = 0; it < 2; ++it) {
            int T = it * 256 + tid;
            int row = T >> 3;
            int off = ((T & 7) << 4) ^ ((row & 7) << 4);
            GLOAD16(Kp + (size_t)(kv * 64 + row) * 128 + off, &lK[buf][0] + T * 16);
            GLOAD16(Vp + (size_t)row * 4096 + kv * 128 + off, &lV[buf][0] + T * 16);
        }
    };

    STAGE(kv0, 0);
    __syncthreads();  // implicit vmcnt(0) drain completes first tile

    for (int kv = kv0; kv < kv1; ++kv) {
        const int cur = (kv - kv0) & 1;
        if (kv + 1 < kv1) STAGE(kv + 1, cur ^ 1);  // prefetch overlaps compute below
        const char* K0 = &lK[cur][0];
        const char* V0 = &lV[cur][0];

        // scores: 16 q x 64 keys per wave (log2 space)
        f32x4_t s[4];
        __builtin_amdgcn_s_setprio(1);
#pragma unroll
        for (int j = 0; j < 4; ++j) {
            int kr = j * 16 + c;
            bf16x8_t k0 = *(const bf16x8_t*)(K0 + kr * 128 + (((g << 4)) ^ ((kr & 7) << 4)));
            bf16x8_t k1 = *(const bf16x8_t*)(K0 + kr * 128 + ((64 + (g << 4)) ^ ((kr & 7) << 4)));
            f32x4_t zz = (f32x4_t){0.f, 0.f, 0.f, 0.f};
            s[j] = __builtin_amdgcn_mfma_f32_16x16x32_bf16(qf0, k0, zz, 0, 0, 0);
            s[j] = __builtin_amdgcn_mfma_f32_16x16x32_bf16(qf1, k1, s[j], 0, 0, 0);
        }
        __builtin_amdgcn_s_setprio(0);
        if (kv == qt) {  // diagonal: zero-fill (NOT -inf) masked entries, keep in softmax
#pragma unroll
            for (int j = 0; j < 4; ++j)
#pragma unroll
                for (int i = 0; i < 4; ++i) {
                    int key = kv * 64 + j * 16 + c;
                    int qr = qt * 64 + w * 16 + g * 4 + i;
                    if (key > qr) s[j][i] = 0.f;
                }
        }
        // --- online softmax, defer-max (THR=11 in log2 space ~ e^7.6) ---
        float pm[4];
#pragma unroll
        for (int i = 0; i < 4; ++i)
            pm[i] = fmaxf(fmaxf(s[0][i], s[1][i]), fmaxf(s[2][i], s[3][i]));
        int ok = 1;
#pragma unroll
        for (int i = 0; i < 4; ++i) ok &= (pm[i] <= m_[i] + 11.f);
        if (__builtin_expect(__all(ok), 1)) {
            // fast path: keep old max, no reduce, no rescale; l_ lane-partial
#pragma unroll
            for (int j = 0; j < 4; ++j)
#pragma unroll
                for (int i = 0; i < 4; ++i) {
                    float p = exp2f(s[j][i] - m_[i]);
                    s[j][i] = p;
                    l_[i] += p;
                }
        } else {
            // slow path (rare): full max-reduce + rescale of lane-partial state
            float mn[4], sc[4];
#pragma unroll
            for (int d = 1; d < 16; d <<= 1)
#pragma unroll
                for (int i = 0; i < 4; ++i) pm[i] = fmaxf(pm[i], __shfl_xor(pm[i], d, 64));
#pragma unroll
            for (int i = 0; i < 4; ++i) {
                mn[i] = fmaxf(m_[i], pm[i]);
                sc[i] = exp2f(m_[i] - mn[i]);
            }
#pragma unroll
            for (int j = 0; j < 4; ++j)
#pragma unroll
                for (int i = 0; i < 4; ++i) {
                    float p = exp2f(s[j][i] - mn[i]);
                    s[j][i] = p;
                }
#pragma unroll
            for (int i = 0; i < 4; ++i) {
                l_[i] = l_[i] * sc[i] + (s[0][i] + s[1][i] + s[2][i] + s[3][i]);
                m_[i] = mn[i];
            }
#pragma unroll
            for (int jd = 0; jd < 4; ++jd)
#pragma unroll
                for (int i = 0; i < 4; ++i) zacc[jd][i] *= sc[i];
        }

        // P -> wave-private swizzled LDS (bf16), then consume as MFMA A-frags
        char* Pw = lP[w];
#pragma unroll
        for (int j = 0; j < 4; ++j)
#pragma unroll
            for (int i = 0; i < 4; ++i) {
                int rq = g * 4 + i;
                *(u16*)(Pw + rq * 128 + (((j << 5) + (c << 1)) ^ ((rq & 7) << 4))) = f2bf_cvt(s[j][i]);
            }
        bf16x8_t pf[2];
#pragma unroll
        for (int kc = 0; kc < 2; ++kc)
            pf[kc] = *(const bf16x8_t*)(Pw + c * 128 + (((kc << 6) + (g << 4)) ^ ((c & 7) << 4)));
        __builtin_amdgcn_s_setprio(1);
#pragma unroll
        for (int jd = 0; jd < 4; ++jd) {
            int vr = jd * 16 + c;
#pragma unroll
            for (int kc = 0; kc < 2; ++kc) {
                bf16x8_t vf = *(const bf16x8_t*)(V0 + vr * 128 + (((kc << 6) + (g << 4)) ^ ((vr & 7) << 4)));
                zacc[jd] = __builtin_amdgcn_mfma_f32_16x16x32_bf16(pf[kc], vf, zacc[jd], 0, 0, 0);
            }
        }
        __builtin_amdgcn_s_setprio(0);
        __syncthreads();  // drains prefetch (vmcnt) + guards buffer reuse
    }

    // epilogue: reduce lane-partial l_ across the 16-lane row group (once)
#pragma unroll
    for (int d = 1; d < 16; d <<= 1)
#pragma unroll
        for (int i = 0; i < 4; ++i) l_[i] += __shfl_xor(l_[i], d, 64);

    const int bb = bh >> 4, hh = bh & 15;
    if (half < 0) {
        // FULL block: suffix fold (Cout zero-score keys) + divide + store Z.
        const int Cout = 2048 - nkv * 64;
        const float* suf = Vsuf + (size_t)bh * 33 * 64 + nkv * 64;
        float s0f[4], lf[4];
#pragma unroll
        for (int i = 0; i < 4; ++i) {
            s0f[i] = exp2f(-m_[i]);           // m_ >= 0 invariant
            lf[i] = l_[i] + (float)Cout * s0f[i];
        }
#pragma unroll
        for (int jd = 0; jd < 4; ++jd) {
            float sv = suf[jd * 16 + c];
#pragma unroll
            for (int i = 0; i < 4; ++i) {
                float z = (zacc[jd][i] + s0f[i] * sv) / lf[i];
                size_t rowz = (size_t)bb * 2048 + qt * 64 + w * 16 + g * 4 + i;
                Z[rowz * 1024 + hh * 64 + jd * 16 + c] = f2bf_cvt(z);
            }
        }
    } else {
        // SPLIT block: write unnormalized partials (merged by attn_combine).
        const int base = (half * 32 + bh) * 2048;
        if (c == 0) {
#pragma unroll
            for (int i = 0; i < 4; ++i) {
                int row = qt * 64 + w * 16 + g * 4 + i;
                Mp[base + row] = m_[i];       // uniform across the 16-lane group
                Lp[base + row] = l_[i];
            }
        }
#pragma unroll
        for (int jd = 0; jd < 4; ++jd)
#pragma unroll
            for (int i = 0; i < 4; ++i) {
                int row = qt * 64 + w * 16 + g * 4 + i;
                Zp[((size_t)(base + row)) * 64 + jd * 16 + c] = f2bf_cvt(zacc[jd][i]);
            }
    }
}

// ---------------------------------------------------------------------------
// 5b. Combine split-KV partials for rows 1024..2047 of each bh:
//     M = max(mA,mB); l = lA*2^(mA-M) + lB*2^(mB-M) + Cout*2^(-M);
//     z = (sA*zA + sB*zB + 2^(-M)*Vsuf) / l.   512 blocks x 256 threads.
// ---------------------------------------------------------------------------
__global__ __launch_bounds__(256) void attn_combine(const u16* __restrict__ Zp,
                                                    const float* __restrict__ Mp,
                                                    const float* __restrict__ Lp,
                                                    const float* __restrict__ Vsuf,
                                                    u16* __restrict__ Z) {
    const int bid = blockIdx.x;             // 512 = 32 bh x 16 segs
    const int bh = bid >> 4, seg = bid & 15, tid = threadIdx.x;
    const int row = 1024 + seg * 64 + (tid >> 2);   // 64 rows per block
    const int q4 = (tid & 3) * 16;                  // dh quarter
    const int qt = row >> 6, nkv = qt + 1, Cout = 2048 - nkv * 64;
    const int baseA = bh * 2048 + row, baseB = (32 + bh) * 2048 + row;
    const float mA = Mp[baseA], lA = Lp[baseA];
    const float mB = Mp[baseB], lB = Lp[baseB];
    const float M = fmaxf(mA, mB);
    const float sA = exp2f(mA - M), sB = exp2f(mB - M), s0 = exp2f(-M);  // M>=0 invariant
    const float lf = lA * sA + lB * sB + (float)Cout * s0;
    const float inv = 1.f / lf;
    const u16* zA = Zp + (size_t)baseA * 64 + q4;
    const u16* zB = Zp + (size_t)baseB * 64 + q4;
    const float* suf = Vsuf + ((size_t)bh * 33 + nkv) * 64 + q4;
    const int bb = bh >> 4, hh = bh & 15;
    u16* dst = Z + ((size_t)bb * 2048 + row) * 1024 + hh * 64 + q4;
#pragma unroll
    for (int d = 0; d < 16; ++d) {
        float z = (sA * bf2f(zA[d]) + sB * bf2f(zB[d]) + s0 * suf[d]) * inv;
        dst[d] = f2bf_cvt(z);
    }
}

// ---------------------------------------------------------------------------
// 6. Output projection GEMM, 64x128 tile: M=4096, N=1024, K=1024. 512 blocks.
// ---------------------------------------------------------------------------
__global__ __launch_bounds__(256) void gemm_out64(const u16* __restrict__ A, const u16* __restrict__ Bm,
                                                  const float* __restrict__ bO,
                                                  const float* __restrict__ resid,
                                                  float* __restrict__ outMid) {
    __shared__ char lA[8192], lB[16384];
    f32x4_t acc[2][4];
#pragma unroll
    for (int ms = 0; ms < 2; ++ms)
#pragma unroll
        for (int ns = 0; ns < 4; ++ns) acc[ms][ns] = (f32x4_t){0.f, 0.f, 0.f, 0.f};
    const int bm = blockIdx.x, bn = blockIdx.y;
    const int tid = threadIdx.x, lane = tid & 63, w = tid >> 6;
    const int wm = w >> 1, wn = w & 1, c = lane & 15, g = lane >> 4;
    const char* Ab = (const char*)A;   // [4096][1024] bf16, row stride 2048 B
    const char* Bb = (const char*)Bm;  // WoT [1024][1024] bf16, row stride 2048 B
    const int rowA0 = bm * 64, rowB0 = bn * 128;
    for (int kt = 0; kt < 16; ++kt) {
#pragma unroll
        for (int it = 0; it < 2; ++it) {       // A: 64 rows x 128 B
            int T = it * 256 + tid;
            int row = T >> 3;
            int off = ((T & 7) << 4) ^ ((row & 7) << 4);
            GLOAD16(Ab + (size_t)(rowA0 + row) * 2048 + (kt << 7) + off, lA + T * 16);
        }
#pragma unroll
        for (int it = 0; it < 4; ++it) {       // B: 128 rows x 128 B
            int T = it * 256 + tid;
            int row = T >> 3;
            int off = ((T & 7) << 4) ^ ((row & 7) << 4);
            GLOAD16(Bb + (size_t)(rowB0 + row) * 2048 + (kt << 7) + off, lB + T * 16);
        }
        __syncthreads();
#pragma unroll
        for (int kc = 0; kc < 2; ++kc) {
            bf16x8_t af[2], bfr[4];
#pragma unroll
            for (int ms = 0; ms < 2; ++ms) {
                int row = wm * 32 + ms * 16 + c;
                af[ms] = *(const bf16x8_t*)(lA + row * 128 + (((kc << 6) + (g << 4)) ^ ((row & 7) << 4)));
            }
#pragma unroll
            for (int ns = 0; ns < 4; ++ns) {
                int row = wn * 64 + ns * 16 + c;
                bfr[ns] = *(const bf16x8_t*)(lB + row * 128 + (((kc << 6) + (g << 4)) ^ ((row & 7) << 4)));
            }
            __builtin_amdgcn_s_setprio(1);
#pragma unroll
            for (int ms = 0; ms < 2; ++ms)
#pragma unroll
                for (int ns = 0; ns < 4; ++ns)
                    acc[ms][ns] = __builtin_amdgcn_mfma_f32_16x16x32_bf16(af[ms], bfr[ns], acc[ms][ns], 0, 0, 0);
            __builtin_amdgcn_s_setprio(0);
        }
        __syncthreads();
    }
#pragma unroll
    for (int ms = 0; ms < 2; ++ms) {
#pragma unroll
        for (int ns = 0; ns < 4; ++ns) {
            int gcol = bn * 128 + wn * 64 + ns * 16 + c;
            float bo = bO[gcol];
#pragma unroll
            for (int i = 0; i < 4; ++i) {
                int grow = bm * 64 + wm * 32 + ms * 16 + g * 4 + i;
                size_t o = (size_t)grow * 1024 + gcol;
                outMid[o] = acc[ms][ns][i] + bo + resid[o];
            }
        }
    }
}

// ---------------------------------------------------------------------------
// 7. LayerNorm #2 + residual: out = mid + LN(mid)*w + b
// ---------------------------------------------------------------------------
__global__ __launch_bounds__(256) void ln2_kernel(const float* __restrict__ mid,
                                                  const float* __restrict__ w,
                                                  const float* __restrict__ b,
                                                  float* __restrict__ out) {
    const int r = blockIdx.x, tid = threadIdx.x, lane = tid & 63, wv = tid >> 6;
    const float4* row = (const float4*)(mid + (size_t)r * 1024);
    float4 v = row[tid];
    float s1 = v.x + v.y + v.z + v.w;
    float s2 = v.x * v.x + v.y * v.y + v.z * v.z + v.w * v.w;
#pragma unroll
    for (int d = 1; d < 64; d <<= 1) { s1 += __shfl_xor(s1, d, 64); s2 += __shfl_xor(s2, d, 64); }
    __shared__ float r1[4], r2[4];
    if (lane == 0) { r1[wv] = s1; r2[wv] = s2; }
    __syncthreads();
    s1 = r1[0] + r1[1] + r1[2] + r1[3];
    s2 = r2[0] + r2[1] + r2[2] + r2[3];
    const float mean = s1 * (1.f / 1024.f);
    const float var  = s2 * (1.f / 1024.f) - mean * mean;
    const float inv  = rsqrtf(var + 1e-5f);
    float4 wv4 = ((const float4*)w)[tid], bv4 = ((const float4*)b)[tid];
    float4 o;
    o.x = v.x + (v.x - mean) * inv * wv4.x + bv4.x;
    o.y = v.y + (v.y - mean) * inv * wv4.y + bv4.y;
    o.z = v.z + (v.z - mean) * inv * wv4.z + bv4.z;
    o.w = v.w + (v.w - mean) * inv * wv4.w + bv4.w;
    ((float4*)(out + (size_t)r * 1024))[tid] = o;
}

// ---------------------------------------------------------------------------
// Launch
// ---------------------------------------------------------------------------
extern "C" void kernel_launch(void* const* d_in, const int* in_sizes, int n_in,
                              void* d_out, int out_size, void* d_ws, size_t ws_size,
                              hipStream_t stream) {
    const float* resid_pre = (const float*)d_in[0];
    const float* W_Q  = (const float*)d_in[1];
    const float* b_Q  = (const float*)d_in[2];
    const float* W_K  = (const float*)d_in[3];
    const float* b_K  = (const float*)d_in[4];
    const float* W_V  = (const float*)d_in[5];
    const float* b_V  = (const float*)d_in[6];
    const float* W_O  = (const float*)d_in[7];
    const float* b_O  = (const float*)d_in[8];
    const float* ln1_w = (const float*)d_in[9];
    const float* ln1_b = (const float*)d_in[10];
    const float* ln2_w = (const float*)d_in[11];
    const float* ln2_b = (const float*)d_in[12];

    char* ws = (char*)d_ws;
    const size_t MB = 1u << 20;
    // Region 0-16MB is triple-used (stream-serialized): x_bf+WqkvT (until
    // gemm_qkv) -> Zp partials (attn -> combine) -> resid_mid (gemm_out64 -> ln2).
    u16*  x_bf   = (u16*)(ws + 0);            // 8 MB
    u16*  WqkvT  = (u16*)(ws + 8 * MB);       // 6 MB
    u16*  Zp     = (u16*)(ws + 0);            // 16 MB split-KV z partials
    float* resid_mid = (float*)(ws + 0);      // 16 MB
    u16*  Qb     = (u16*)(ws + 16 * MB);      // 8 MB
    u16*  Kb     = (u16*)(ws + 24 * MB);      // 8 MB
    u16*  Vb     = (u16*)(ws + 32 * MB);      // 8 MB
    u16*  Vt     = (u16*)(ws + 40 * MB);      // 8 MB
    float* Vsuf  = (float*)(ws + 48 * MB);            // 270 KB
    float* Psum  = (float*)(ws + 48 * MB + 512 * 1024); // 256 KB
    u16*  Zb     = (u16*)(ws + 49 * MB);      // 8 MB
    u16*  WoT    = (u16*)(ws + 57 * MB);      // 2 MB
    float* Mp    = (float*)(ws + 59 * MB);            // 512 KB [2][32][2048]
    float* Lp    = (float*)(ws + 59 * MB + 512 * 1024); // 512 KB

    ln1_kernel<<<dim3(4096), dim3(256), 0, stream>>>(resid_pre, ln1_w, ln1_b, x_bf);

    transpose_w<<<dim3(16, 1, 16), dim3(256), 0, stream>>>(W_Q, WqkvT,                1024, 64);
    transpose_w<<<dim3(16, 1, 16), dim3(256), 0, stream>>>(W_K, WqkvT + 1024 * 1024,  1024, 64);
    transpose_w<<<dim3(16, 1, 16), dim3(256), 0, stream>>>(W_V, WqkvT + 2048 * 1024,  1024, 64);
    transpose_w<<<dim3(16, 16, 1), dim3(256), 0, stream>>>(W_O, WoT, 1024, 1024);

    gemm_qkv<<<dim3(32, 24), dim3(256), 0, stream>>>(x_bf, WqkvT, b_Q, b_K, b_V, Qb, Kb, Vb);

    vtrans_psum<<<dim3(32, 32), dim3(256), 0, stream>>>(Vb, Vt, Psum);
    vsuffix<<<dim3(32), dim3(64), 0, stream>>>(Psum, Vsuf);

    attn_kernel<<<dim3(1536), dim3(256), 0, stream>>>(Qb, Kb, Vt, Vsuf, Zb, Zp, Mp, Lp);
    attn_combine<<<dim3(512), dim3(256), 0, stream>>>(Zp, Mp, Lp, Vsuf, Zb);

    gemm_out64<<<dim3(64, 8), dim3(256), 0, stream>>>(Zb, WoT, b_O, resid_pre, resid_mid);

    ln2_kernel<<<dim3(4096), dim3(256), 0, stream>>>(resid_mid, ln2_w, ln2_b, (float*)d_out);
}